// Round 2
// baseline (573.141 us; speedup 1.0000x reference)
//
#include <hip/hip_runtime.h>

#define T_LEN 256
#define B_TOT 8192
#define RSCALE 3.2734375f
#define L2E    1.44269504f
#define LN2    0.693147180559945f

typedef __attribute__((ext_vector_type(2))) _Float16 h2;

__device__ __forceinline__ h2 pkrtz(float lo, float hi) {
    return __builtin_bit_cast(h2, __builtin_amdgcn_cvt_pkrtz(lo, hi));
}
__device__ __forceinline__ float ror8f(float x) {
    int xi = __float_as_int(x);
    int r = __builtin_amdgcn_update_dpp(xi, xi, 0x128, 0xF, 0xF, false); // ROW_ROR:8
    return __int_as_float(r);
}
// direct rotate-by-N within the 16-lane row (one DPP, independent of chain)
#define RORH(x, N) __builtin_bit_cast(h2, __builtin_amdgcn_update_dpp( \
        __builtin_bit_cast(int, (x)), __builtin_bit_cast(int, (x)),    \
        0x120 + (N), 0xF, 0xF, false))

// ---------------- pack: ctrl byte (tag | tidx<<4) + gold trans/start part (no em gather) ----
__global__ __launch_bounds__(256) void pack_ctrl(
    const int* __restrict__ tags, const int* __restrict__ w2w,
    const int* __restrict__ ic,   const int* __restrict__ ds,
    const float* __restrict__ cw, const float* __restrict__ trans,
    const float* __restrict__ start,
    unsigned char* __restrict__ ctrl, float* __restrict__ goldp)
{
    int idx = blockIdx.x * 256 + threadIdx.x;   // b*256 + t
    int b = idx >> 8, t = idx & 255;
    int tag = tags[idx];
    unsigned char byte = (unsigned char)tag;
    float g;
    if (t == 0) {
        g = cw[tag] * start[tag];
    } else {
        int off = b * (T_LEN - 1) + (t - 1);
        int tidx = (w2w[off] == 1) ? 0 : ((ic[off] == 0) ? 1 : ((ds[off] == 0) ? 2 : 3));
        byte |= (unsigned char)(tidx << 4);
        g = cw[tag] * trans[tidx * 256 + tags[idx - 1] * 16 + tag];
    }
    ctrl[idx]  = byte;
    goldp[idx] = g;
}

// ---------------- recurrence: 4 seqs/wave, 2048 waves, dot2-f16 matvec ----------------
__global__ __launch_bounds__(256, 2) void crf_rec(
    const float* __restrict__ em, const float* __restrict__ trans,
    const float* __restrict__ start, const float* __restrict__ cw,
    const unsigned char* __restrict__ ctrl,
    float* __restrict__ gev, float* __restrict__ out)
{
    __shared__ float tl[1024];
    for (int i = threadIdx.x; i < 1024; i += 256) tl[i] = trans[i];
    __syncthreads();

    const int j   = threadIdx.x & 15;
    const int seq = (blockIdx.x * 256 + threadIdx.x) >> 4;

    // DPP rotation-direction probe (proven in R1/R2)
    int pr    = __builtin_amdgcn_update_dpp(j, j, 0x121, 0xF, 0xF, false);
    int delta = (pr - j) & 15;

    // half2 diagonal tables: D[c][r] = ( E_c[(j+r*d)&15][j] , E_c[(j+(r+8)*d)&15][j] )
    h2 D[4][8];
#pragma unroll
    for (int c = 0; c < 4; ++c)
#pragma unroll
        for (int r = 0; r < 8; ++r) {
            float lo = __expf(tl[c * 256 + ((j + r * delta) & 15) * 16 + j]);
            float hi = __expf(tl[c * 256 + ((j + (r + 8) * delta) & 15) * 16 + j]);
            D[c][r] = pkrtz(lo, hi);
        }

    const float cw_j = cw[j];
    const float st_j = start[j];
    const float* ep  = em + (size_t)seq * 4096 + j;
    const uint4* cp  = (const uint4*)(ctrl + (size_t)seq * 256);

    // 16-deep emission ring (1 f32/lane/step)
    float emr[16];
#pragma unroll
    for (int k = 0; k < 16; ++k) emr[k] = ep[k * 16];
    uint4 cq = cp[0], cqn = cp[1];

    float u, ge, logC = 5.545177444479562f;   // 8*ln2: u0 pre-scaled 2^-8
    {
        int tag0 = (int)(cq.x & 15u);
        u  = __expf(st_j + emr[0]) * 0.00390625f;
        ge = (j == tag0) ? cw_j * emr[0] : 0.0f;
        emr[0] = ep[16 * 16];                  // refill slot 0 with t=16
    }

    auto STEP = [&](int t, int k, bool pf) __attribute__((always_inline)) {
        unsigned dw = (k < 4) ? cq.x : (k < 8) ? cq.y : (k < 12) ? cq.z : cq.w;
        int sh = 8 * (k & 3);
        int tag   = (int)((dw >> sh) & 15u);
        bool modd = ((dw >> (sh + 4)) & 1u) != 0u;   // tidx odd
        bool mhi  = ((dw >> (sh + 5)) & 1u) != 0u;   // tidx >= 2

        // pair (u_j, u_{j+8d}) in f16; ALL 8 rotations computed independently
        // from P0 (parallel DPPs), dots split into 4 independent chains.
        float uh = ror8f(u);
        h2 P0 = pkrtz(u, uh);
        h2 P1 = RORH(P0, 1), P2 = RORH(P0, 2), P3 = RORH(P0, 3),
           P4 = RORH(P0, 4), P5 = RORH(P0, 5), P6 = RORH(P0, 6),
           P7 = RORH(P0, 7);
#define ESEL(r) (mhi ? (modd ? D[3][r] : D[2][r]) : (modd ? D[1][r] : D[0][r]))
        float s0 = __builtin_amdgcn_fdot2(P0, ESEL(0), 0.0f, false);
        float s1 = __builtin_amdgcn_fdot2(P1, ESEL(1), 0.0f, false);
        float s2 = __builtin_amdgcn_fdot2(P2, ESEL(2), 0.0f, false);
        float s3 = __builtin_amdgcn_fdot2(P3, ESEL(3), 0.0f, false);
        s0 = __builtin_amdgcn_fdot2(P4, ESEL(4), s0, false);
        s1 = __builtin_amdgcn_fdot2(P5, ESEL(5), s1, false);
        s2 = __builtin_amdgcn_fdot2(P6, ESEL(6), s2, false);
        s3 = __builtin_amdgcn_fdot2(P7, ESEL(7), s3, false);
#undef ESEL
        float s = (s0 + s1) + (s2 + s3);
        float exf = __builtin_exp2f(fmaf(emr[k], L2E, -RSCALE * L2E));
        if (j == tag) ge = fmaf(cw_j, emr[k], ge);   // gold em-term
        u = s * exf;
        if (pf) emr[k] = ep[(size_t)(t + 16) * 16];  // refill 16 steps ahead
        if ((k & 7) == 7) {                          // exact pow2 renorm, -4 bias
            float mx = u;
            mx = fmaxf(mx, __shfl_xor(mx, 1, 64));
            mx = fmaxf(mx, __shfl_xor(mx, 2, 64));
            mx = fmaxf(mx, __shfl_xor(mx, 4, 64));
            mx = fmaxf(mx, __shfl_xor(mx, 8, 64));
            // frexp/ldexp via exponent-field bit ops (mx > 0, normal)
            int eb = (__float_as_int(mx) >> 23) & 255;     // e2 = eb - 126
            u *= __int_as_float((249 - eb) << 23);          // u * 2^(-e2-4)
            logC += (float)(eb - 122) * LN2;                // (e2+4)*ln2
        }
    };

    // block 0: t=1..15
#pragma unroll
    for (int k = 1; k < 16; ++k) STEP(k, k, true);
    // blocks 1..14 with prefetch
    for (int blk = 1; blk < 15; ++blk) {
        cq = cqn;
        cqn = cp[blk + 1];
#pragma unroll
        for (int k = 0; k < 16; ++k) STEP(blk * 16 + k, k, true);
    }
    // peeled last block: t=240..255, no prefetch
    cq = cqn;
#pragma unroll
    for (int k = 0; k < 16; ++k) STEP(240 + k, k, false);

    // group reductions
    float su = u, gs = ge;
#pragma unroll
    for (int m = 1; m < 16; m <<= 1) {
        su += __shfl_xor(su, m, 64);
        gs += __shfl_xor(gs, m, 64);
    }
    if (j == 0) {
        gev[seq] = gs;
        out[B_TOT + seq] = logf(su) + 255.0f * RSCALE + logC;
    }
}

// ---------------- gold reduction ----------------
__global__ __launch_bounds__(256) void gold_red(
    const float* __restrict__ goldp, const float* __restrict__ gev,
    float* __restrict__ out)
{
    int b = blockIdx.x * 4 + (threadIdx.x >> 6);
    int l = threadIdx.x & 63;
    const float* p = goldp + (size_t)b * 256;
    float s = (p[l] + p[l + 64]) + (p[l + 128] + p[l + 192]);
#pragma unroll
    for (int m = 1; m < 64; m <<= 1) s += __shfl_xor(s, m, 64);
    if (l == 0) out[b] = s + gev[b];
}

extern "C" void kernel_launch(void* const* d_in, const int* in_sizes, int n_in,
                              void* d_out, int out_size, void* d_ws, size_t ws_size,
                              hipStream_t stream) {
    const float* emissions     = (const float*)d_in[0];
    const int*   tags          = (const int*)  d_in[1];
    const int*   who2who       = (const int*)  d_in[2];
    const int*   init_count    = (const int*)  d_in[3];
    const int*   distance      = (const int*)  d_in[4];
    const float* class_weights = (const float*)d_in[5];
    const float* trans_stack   = (const float*)d_in[6];
    const float* start_scores  = (const float*)d_in[7];
    float* out = (float*)d_out;

    char* ws = (char*)d_ws;
    unsigned char* ctrl  = (unsigned char*)ws;           // 2 MB
    float* goldp = (float*)(ws + (2 << 20));             // 8 MB
    float* gev   = (float*)(ws + (10 << 20));            // 32 KB

    hipLaunchKernelGGL(pack_ctrl, dim3(B_TOT), dim3(256), 0, stream,
                       tags, who2who, init_count, distance,
                       class_weights, trans_stack, start_scores, ctrl, goldp);

    hipLaunchKernelGGL(crf_rec, dim3(B_TOT * 16 / 256), dim3(256), 0, stream,
                       emissions, trans_stack, start_scores, class_weights,
                       ctrl, gev, out);

    hipLaunchKernelGGL(gold_red, dim3(B_TOT / 4), dim3(256), 0, stream,
                       goldp, gev, out);
}

// Round 3
// 255.103 us; speedup vs baseline: 2.2467x; 2.2467x over previous
//
#include <hip/hip_runtime.h>

#define T_LEN 256
#define B_TOT 8192
#define RSCALE 3.2734375f
#define L2E    1.44269504f
#define LN2    0.693147180559945f

typedef __attribute__((ext_vector_type(2))) _Float16 h2;

__device__ __forceinline__ h2 pkrtz(float lo, float hi) {
    return __builtin_bit_cast(h2, __builtin_amdgcn_cvt_pkrtz(lo, hi));
}
__device__ __forceinline__ float ror8f(float x) {
    int xi = __float_as_int(x);
    int r = __builtin_amdgcn_update_dpp(xi, xi, 0x128, 0xF, 0xF, false); // ROW_ROR:8
    return __int_as_float(r);
}
__device__ __forceinline__ h2 ror1h(h2 x) {
    int xi = __builtin_bit_cast(int, x);
    int r = __builtin_amdgcn_update_dpp(xi, xi, 0x121, 0xF, 0xF, false); // ROW_ROR:1
    return __builtin_bit_cast(h2, r);
}
__device__ __forceinline__ h2 ror4h(h2 x) {
    int xi = __builtin_bit_cast(int, x);
    int r = __builtin_amdgcn_update_dpp(xi, xi, 0x124, 0xF, 0xF, false); // ROW_ROR:4
    return __builtin_bit_cast(h2, r);
}

// ---------------- pack: ctrl byte (tag | tidx<<4) + gold trans/start part (no em gather) ----
__global__ __launch_bounds__(256) void pack_ctrl(
    const int* __restrict__ tags, const int* __restrict__ w2w,
    const int* __restrict__ ic,   const int* __restrict__ ds,
    const float* __restrict__ cw, const float* __restrict__ trans,
    const float* __restrict__ start,
    unsigned char* __restrict__ ctrl, float* __restrict__ goldp)
{
    int idx = blockIdx.x * 256 + threadIdx.x;   // b*256 + t
    int b = idx >> 8, t = idx & 255;
    int tag = tags[idx];
    unsigned char byte = (unsigned char)tag;
    float g;
    if (t == 0) {
        g = cw[tag] * start[tag];
    } else {
        int off = b * (T_LEN - 1) + (t - 1);
        int tidx = (w2w[off] == 1) ? 0 : ((ic[off] == 0) ? 1 : ((ds[off] == 0) ? 2 : 3));
        byte |= (unsigned char)(tidx << 4);
        g = cw[tag] * trans[tidx * 256 + tags[idx - 1] * 16 + tag];
    }
    ctrl[idx]  = byte;
    goldp[idx] = g;
}

// ---------------- recurrence: 4 seqs/wave, 2048 waves, dot2-f16 matvec ----------------
__global__ __launch_bounds__(256, 2) void crf_rec(
    const float* __restrict__ em, const float* __restrict__ trans,
    const float* __restrict__ start, const float* __restrict__ cw,
    const unsigned char* __restrict__ ctrl,
    float* __restrict__ gev, float* __restrict__ out)
{
    __shared__ float tl[1024];
    for (int i = threadIdx.x; i < 1024; i += 256) tl[i] = trans[i];
    __syncthreads();

    const int j   = threadIdx.x & 15;
    const int seq = (blockIdx.x * 256 + threadIdx.x) >> 4;

    // DPP rotation-direction probe (proven in R1/R2)
    int pr    = __builtin_amdgcn_update_dpp(j, j, 0x121, 0xF, 0xF, false);
    int delta = (pr - j) & 15;

    // half2 diagonal tables: D[c][r] = ( E_c[(j+r*d)&15][j] , E_c[(j+(r+8)*d)&15][j] )
    h2 D[4][8];
#pragma unroll
    for (int c = 0; c < 4; ++c)
#pragma unroll
        for (int r = 0; r < 8; ++r) {
            float lo = __expf(tl[c * 256 + ((j + r * delta) & 15) * 16 + j]);
            float hi = __expf(tl[c * 256 + ((j + (r + 8) * delta) & 15) * 16 + j]);
            D[c][r] = pkrtz(lo, hi);
        }

    const float cw_j = cw[j];
    const float st_j = start[j];
    const float* ep  = em + (size_t)seq * 4096 + j;
    const uint4* cp  = (const uint4*)(ctrl + (size_t)seq * 256);

    // 16-deep emission ring (1 f32/lane/step)
    float emr[16];
#pragma unroll
    for (int k = 0; k < 16; ++k) emr[k] = ep[k * 16];
    uint4 cq = cp[0], cqn = cp[1];

    float u, ge, logC = 5.545177444479562f;   // 8*ln2: u0 pre-scaled 2^-8
    {
        int tag0 = (int)(cq.x & 15u);
        u  = __expf(st_j + emr[0]) * 0.00390625f;
        ge = (j == tag0) ? cw_j * emr[0] : 0.0f;
        emr[0] = ep[16 * 16];                  // refill slot 0 with t=16
    }

    auto STEP = [&](int t, int k, bool pf) __attribute__((always_inline)) {
        unsigned dw = (k < 4) ? cq.x : (k < 8) ? cq.y : (k < 12) ? cq.z : cq.w;
        int sh = 8 * (k & 3);
        int tag   = (int)((dw >> sh) & 15u);
        bool modd = ((dw >> (sh + 4)) & 1u) != 0u;   // tidx odd
        bool mhi  = ((dw >> (sh + 5)) & 1u) != 0u;   // tidx >= 2

        // pair (u_j, u_{j+8d}) in f16; TWO serial ror1 chains (rot 0..3 and 4..7)
        // halve the dependency depth vs one 8-deep chain; +2 live regs only.
        float uh = ror8f(u);
        h2 P = pkrtz(u, uh);
        h2 Q = ror4h(P);
        float s0 = 0.0f, s1 = 0.0f;
#pragma unroll
        for (int r = 0; r < 4; ++r) {
            if (r) { P = ror1h(P); Q = ror1h(Q); }
            h2 e01 = modd ? D[1][r] : D[0][r];
            h2 e23 = modd ? D[3][r] : D[2][r];
            h2 e   = mhi ? e23 : e01;
            s0 = __builtin_amdgcn_fdot2(P, e, s0, false);
            h2 f01 = modd ? D[1][r + 4] : D[0][r + 4];
            h2 f23 = modd ? D[3][r + 4] : D[2][r + 4];
            h2 f   = mhi ? f23 : f01;
            s1 = __builtin_amdgcn_fdot2(Q, f, s1, false);
        }
        float s = s0 + s1;
        float exf = __builtin_exp2f(fmaf(emr[k], L2E, -RSCALE * L2E));
        if (j == tag) ge = fmaf(cw_j, emr[k], ge);   // gold em-term
        u = s * exf;
        if (pf) emr[k] = ep[(size_t)(t + 16) * 16];  // refill 16 steps ahead
        if ((k & 7) == 7) {                          // exact pow2 renorm, -4 bias
            float mx = u;
            mx = fmaxf(mx, __shfl_xor(mx, 1, 64));
            mx = fmaxf(mx, __shfl_xor(mx, 2, 64));
            mx = fmaxf(mx, __shfl_xor(mx, 4, 64));
            mx = fmaxf(mx, __shfl_xor(mx, 8, 64));
            // frexp/ldexp via exponent-field bit ops (mx > 0, normal);
            // correctness verified in R2 run (passed, absmax unchanged)
            int eb = (__float_as_int(mx) >> 23) & 255;   // e2 = eb - 126
            u *= __int_as_float((249 - eb) << 23);        // u * 2^(-e2-4)
            logC += (float)(eb - 122) * LN2;              // (e2+4)*ln2
        }
    };

    // block 0: t=1..15
#pragma unroll
    for (int k = 1; k < 16; ++k) STEP(k, k, true);
    // blocks 1..14 with prefetch
    for (int blk = 1; blk < 15; ++blk) {
        cq = cqn;
        cqn = cp[blk + 1];
#pragma unroll
        for (int k = 0; k < 16; ++k) STEP(blk * 16 + k, k, true);
    }
    // peeled last block: t=240..255, no prefetch
    cq = cqn;
#pragma unroll
    for (int k = 0; k < 16; ++k) STEP(240 + k, k, false);

    // group reductions
    float su = u, gs = ge;
#pragma unroll
    for (int m = 1; m < 16; m <<= 1) {
        su += __shfl_xor(su, m, 64);
        gs += __shfl_xor(gs, m, 64);
    }
    if (j == 0) {
        gev[seq] = gs;
        out[B_TOT + seq] = logf(su) + 255.0f * RSCALE + logC;
    }
}

// ---------------- gold reduction ----------------
__global__ __launch_bounds__(256) void gold_red(
    const float* __restrict__ goldp, const float* __restrict__ gev,
    float* __restrict__ out)
{
    int b = blockIdx.x * 4 + (threadIdx.x >> 6);
    int l = threadIdx.x & 63;
    const float* p = goldp + (size_t)b * 256;
    float s = (p[l] + p[l + 64]) + (p[l + 128] + p[l + 192]);
#pragma unroll
    for (int m = 1; m < 64; m <<= 1) s += __shfl_xor(s, m, 64);
    if (l == 0) out[b] = s + gev[b];
}

extern "C" void kernel_launch(void* const* d_in, const int* in_sizes, int n_in,
                              void* d_out, int out_size, void* d_ws, size_t ws_size,
                              hipStream_t stream) {
    const float* emissions     = (const float*)d_in[0];
    const int*   tags          = (const int*)  d_in[1];
    const int*   who2who       = (const int*)  d_in[2];
    const int*   init_count    = (const int*)  d_in[3];
    const int*   distance      = (const int*)  d_in[4];
    const float* class_weights = (const float*)d_in[5];
    const float* trans_stack   = (const float*)d_in[6];
    const float* start_scores  = (const float*)d_in[7];
    float* out = (float*)d_out;

    char* ws = (char*)d_ws;
    unsigned char* ctrl  = (unsigned char*)ws;           // 2 MB
    float* goldp = (float*)(ws + (2 << 20));             // 8 MB
    float* gev   = (float*)(ws + (10 << 20));            // 32 KB

    hipLaunchKernelGGL(pack_ctrl, dim3(B_TOT), dim3(256), 0, stream,
                       tags, who2who, init_count, distance,
                       class_weights, trans_stack, start_scores, ctrl, goldp);

    hipLaunchKernelGGL(crf_rec, dim3(B_TOT * 16 / 256), dim3(256), 0, stream,
                       emissions, trans_stack, start_scores, class_weights,
                       ctrl, gev, out);

    hipLaunchKernelGGL(gold_red, dim3(B_TOT / 4), dim3(256), 0, stream,
                       goldp, gev, out);
}

// Round 4
// 233.972 us; speedup vs baseline: 2.4496x; 1.0903x over previous
//
#include <hip/hip_runtime.h>

#define T_LEN 256
#define B_TOT 8192
#define RSCALE 3.2734375f
#define L2E    1.44269504f
#define LN2    0.693147180559945f

typedef __attribute__((ext_vector_type(2))) _Float16 h2;

__device__ __forceinline__ h2 pkrtz(float lo, float hi) {
    return __builtin_bit_cast(h2, __builtin_amdgcn_cvt_pkrtz(lo, hi));
}
__device__ __forceinline__ h2 h2cast(unsigned x) {
    return __builtin_bit_cast(h2, x);
}
__device__ __forceinline__ float ror8f(float x) {
    int xi = __float_as_int(x);
    int r = __builtin_amdgcn_update_dpp(xi, xi, 0x128, 0xF, 0xF, false); // ROW_ROR:8
    return __int_as_float(r);
}
__device__ __forceinline__ h2 ror1h(h2 x) {
    int xi = __builtin_bit_cast(int, x);
    int r = __builtin_amdgcn_update_dpp(xi, xi, 0x121, 0xF, 0xF, false); // ROW_ROR:1
    return __builtin_bit_cast(h2, r);
}
__device__ __forceinline__ h2 ror4h(h2 x) {
    int xi = __builtin_bit_cast(int, x);
    int r = __builtin_amdgcn_update_dpp(xi, xi, 0x124, 0xF, 0xF, false); // ROW_ROR:4
    return __builtin_bit_cast(h2, r);
}

// ---------------- pack: ctrl byte (tag | tidx<<4) + gold trans/start part (no em gather) ----
__global__ __launch_bounds__(256) void pack_ctrl(
    const int* __restrict__ tags, const int* __restrict__ w2w,
    const int* __restrict__ ic,   const int* __restrict__ ds,
    const float* __restrict__ cw, const float* __restrict__ trans,
    const float* __restrict__ start,
    unsigned char* __restrict__ ctrl, float* __restrict__ goldp)
{
    int idx = blockIdx.x * 256 + threadIdx.x;   // b*256 + t
    int b = idx >> 8, t = idx & 255;
    int tag = tags[idx];
    unsigned char byte = (unsigned char)tag;
    float g;
    if (t == 0) {
        g = cw[tag] * start[tag];
    } else {
        int off = b * (T_LEN - 1) + (t - 1);
        int tidx = (w2w[off] == 1) ? 0 : ((ic[off] == 0) ? 1 : ((ds[off] == 0) ? 2 : 3));
        byte |= (unsigned char)(tidx << 4);
        g = cw[tag] * trans[tidx * 256 + tags[idx - 1] * 16 + tag];
    }
    ctrl[idx]  = byte;
    goldp[idx] = g;
}

// ---------------- recurrence: 4 seqs/wave, 2048 waves, dot2-f16 matvec ----------------
// Table select moved from VALU (24 cndmask/step) to LDS: Dl[c][j][r] h2, fetched
// as two ds_read_b128 per step, prefetched one step ahead (ctrl known in advance).
__global__ __launch_bounds__(256, 2) void crf_rec(
    const float* __restrict__ em, const float* __restrict__ trans,
    const float* __restrict__ start, const float* __restrict__ cw,
    const unsigned char* __restrict__ ctrl,
    float* __restrict__ gev, float* __restrict__ out)
{
    __shared__ float tl[1024];
    __shared__ __align__(16) unsigned char Dl[3072];  // [c]*768 + [j]*48 + [r]*4, h2 entries

    for (int i = threadIdx.x; i < 1024; i += 256) tl[i] = trans[i];
    __syncthreads();

    const int j = threadIdx.x & 15;

    // DPP rotation-direction probe (proven in R1/R2); delta is lane-uniform
    int pr    = __builtin_amdgcn_update_dpp(j, j, 0x121, 0xF, 0xF, false);
    int delta = (pr - j) & 15;

    // Build Dl: 256 threads x 2 entries = 4*16*8 h2
    {
        int c  = threadIdx.x >> 6;
        int jj = (threadIdx.x >> 2) & 15;
        int r0 = (threadIdx.x & 3) * 2;
#pragma unroll
        for (int q = 0; q < 2; ++q) {
            int r = r0 + q;
            float lo = __expf(tl[c * 256 + ((jj + r * delta) & 15) * 16 + jj]);
            float hi = __expf(tl[c * 256 + ((jj + (r + 8) * delta) & 15) * 16 + jj]);
            *(h2*)&Dl[c * 768 + jj * 48 + r * 4] = pkrtz(lo, hi);
        }
    }
    __syncthreads();

    const int seq = (blockIdx.x * 256 + threadIdx.x) >> 4;
    const float cw_j = cw[j];
    const float st_j = start[j];
    const float* ep  = em + (size_t)seq * 4096 + j;
    const uint4* cp  = (const uint4*)(ctrl + (size_t)seq * 256);
    const unsigned char* Dbase = &Dl[j * 48];

    // 16-deep emission ring (1 f32/lane/step)
    float emr[16];
#pragma unroll
    for (int k = 0; k < 16; ++k) emr[k] = ep[k * 16];
    uint4 cq = cp[0], cqn = cp[1];

    // ping-pong E-row buffers (compile-time indexed only)
    uint4 qa[2], qb[2];

    float u, ge, logC = 5.545177444479562f;   // 8*ln2: u0 pre-scaled 2^-8
    {
        int tag0 = (int)(cq.x & 15u);
        u  = __expf(st_j + emr[0]) * 0.00390625f;
        ge = (j == tag0) ? cw_j * emr[0] : 0.0f;
        emr[0] = ep[16 * 16];                  // refill slot 0 with t=16
        // prefetch E-row for step k=1 (tidx bits at dword0 bits 12-13)
        unsigned cn = (cq.x >> 12) & 3u;
        const uint4* pn = (const uint4*)(Dbase + cn * 768);
        qa[1] = pn[0];
        qb[1] = pn[1];
    }

    auto STEP = [&](int t, int k, bool pf) __attribute__((always_inline)) {
        // ---- prefetch next step's E-row (ping-pong slot (k+1)&1) ----
        {
            int kk = k + 1;                                // window pos 1..16
            const uint4& qn = (kk < 16) ? cq : cqn;
            int km = kk & 15;
            unsigned dwn = (km < 4) ? qn.x : (km < 8) ? qn.y : (km < 12) ? qn.z : qn.w;
            unsigned cn = (dwn >> (8 * (km & 3) + 4)) & 3u;
            const uint4* pn = (const uint4*)(Dbase + cn * 768);
            qa[(k + 1) & 1] = pn[0];
            qb[(k + 1) & 1] = pn[1];
        }
        unsigned dw = (k < 4) ? cq.x : (k < 8) ? cq.y : (k < 12) ? cq.z : cq.w;
        int sh = 8 * (k & 3);
        int tag = (int)((dw >> sh) & 15u);

        // pair (u_j, u_{j+8d}) in f16; two serial ror1 chains (rot 0..3 / 4..7)
        uint4 A = qa[k & 1], B = qb[k & 1];
        float uh = ror8f(u);
        h2 P = pkrtz(u, uh);
        h2 Q = ror4h(P);
        float s0 = __builtin_amdgcn_fdot2(P, h2cast(A.x), 0.0f, false);
        float s1 = __builtin_amdgcn_fdot2(Q, h2cast(B.x), 0.0f, false);
        P = ror1h(P); Q = ror1h(Q);
        s0 = __builtin_amdgcn_fdot2(P, h2cast(A.y), s0, false);
        s1 = __builtin_amdgcn_fdot2(Q, h2cast(B.y), s1, false);
        P = ror1h(P); Q = ror1h(Q);
        s0 = __builtin_amdgcn_fdot2(P, h2cast(A.z), s0, false);
        s1 = __builtin_amdgcn_fdot2(Q, h2cast(B.z), s1, false);
        P = ror1h(P); Q = ror1h(Q);
        s0 = __builtin_amdgcn_fdot2(P, h2cast(A.w), s0, false);
        s1 = __builtin_amdgcn_fdot2(Q, h2cast(B.w), s1, false);
        float s = s0 + s1;
        float exf = __builtin_exp2f(fmaf(emr[k], L2E, -RSCALE * L2E));
        if (j == tag) ge = fmaf(cw_j, emr[k], ge);   // gold em-term
        u = s * exf;
        if (pf) emr[k] = ep[(size_t)(t + 16) * 16];  // refill 16 steps ahead
        if ((k & 7) == 7) {                          // exact pow2 renorm, -4 bias
            float mx = u;
            mx = fmaxf(mx, __shfl_xor(mx, 1, 64));
            mx = fmaxf(mx, __shfl_xor(mx, 2, 64));
            mx = fmaxf(mx, __shfl_xor(mx, 4, 64));
            mx = fmaxf(mx, __shfl_xor(mx, 8, 64));
            // frexp/ldexp via exponent-field bit ops (mx > 0, normal); proven R3
            int eb = (__float_as_int(mx) >> 23) & 255;   // e2 = eb - 126
            u *= __int_as_float((249 - eb) << 23);        // u * 2^(-e2-4)
            logC += (float)(eb - 122) * LN2;              // (e2+4)*ln2
        }
    };

    // block 0: t=1..15
#pragma unroll
    for (int k = 1; k < 16; ++k) STEP(k, k, true);
    // blocks 1..14 with prefetch
    for (int blk = 1; blk < 15; ++blk) {
        cq = cqn;
        cqn = cp[blk + 1];
#pragma unroll
        for (int k = 0; k < 16; ++k) STEP(blk * 16 + k, k, true);
    }
    // peeled last block: t=240..255, no em prefetch (E-prefetch reads stale cqn: harmless)
    cq = cqn;
#pragma unroll
    for (int k = 0; k < 16; ++k) STEP(240 + k, k, false);

    // group reductions
    float su = u, gs = ge;
#pragma unroll
    for (int m = 1; m < 16; m <<= 1) {
        su += __shfl_xor(su, m, 64);
        gs += __shfl_xor(gs, m, 64);
    }
    if (j == 0) {
        gev[seq] = gs;
        out[B_TOT + seq] = logf(su) + 255.0f * RSCALE + logC;
    }
}

// ---------------- gold reduction ----------------
__global__ __launch_bounds__(256) void gold_red(
    const float* __restrict__ goldp, const float* __restrict__ gev,
    float* __restrict__ out)
{
    int b = blockIdx.x * 4 + (threadIdx.x >> 6);
    int l = threadIdx.x & 63;
    const float* p = goldp + (size_t)b * 256;
    float s = (p[l] + p[l + 64]) + (p[l + 128] + p[l + 192]);
#pragma unroll
    for (int m = 1; m < 64; m <<= 1) s += __shfl_xor(s, m, 64);
    if (l == 0) out[b] = s + gev[b];
}

extern "C" void kernel_launch(void* const* d_in, const int* in_sizes, int n_in,
                              void* d_out, int out_size, void* d_ws, size_t ws_size,
                              hipStream_t stream) {
    const float* emissions     = (const float*)d_in[0];
    const int*   tags          = (const int*)  d_in[1];
    const int*   who2who       = (const int*)  d_in[2];
    const int*   init_count    = (const int*)  d_in[3];
    const int*   distance      = (const int*)  d_in[4];
    const float* class_weights = (const float*)d_in[5];
    const float* trans_stack   = (const float*)d_in[6];
    const float* start_scores  = (const float*)d_in[7];
    float* out = (float*)d_out;

    char* ws = (char*)d_ws;
    unsigned char* ctrl  = (unsigned char*)ws;           // 2 MB
    float* goldp = (float*)(ws + (2 << 20));             // 8 MB
    float* gev   = (float*)(ws + (10 << 20));            // 32 KB

    hipLaunchKernelGGL(pack_ctrl, dim3(B_TOT), dim3(256), 0, stream,
                       tags, who2who, init_count, distance,
                       class_weights, trans_stack, start_scores, ctrl, goldp);

    hipLaunchKernelGGL(crf_rec, dim3(B_TOT * 16 / 256), dim3(256), 0, stream,
                       emissions, trans_stack, start_scores, class_weights,
                       ctrl, gev, out);

    hipLaunchKernelGGL(gold_red, dim3(B_TOT / 4), dim3(256), 0, stream,
                       goldp, gev, out);
}

// Round 5
// 232.307 us; speedup vs baseline: 2.4672x; 1.0072x over previous
//
#include <hip/hip_runtime.h>

#define T_LEN 256
#define B_TOT 8192
#define RSCALE 3.2734375f
#define L2E    1.44269504f
#define LN2    0.693147180559945f

typedef __attribute__((ext_vector_type(2))) _Float16 h2;

__device__ __forceinline__ h2 pkrtz(float lo, float hi) {
    return __builtin_bit_cast(h2, __builtin_amdgcn_cvt_pkrtz(lo, hi));
}
__device__ __forceinline__ h2 h2cast(unsigned x) {
    return __builtin_bit_cast(h2, x);
}
__device__ __forceinline__ float ror8f(float x) {
    int xi = __float_as_int(x);
    int r = __builtin_amdgcn_update_dpp(xi, xi, 0x128, 0xF, 0xF, false); // ROW_ROR:8
    return __int_as_float(r);
}
__device__ __forceinline__ h2 ror1h(h2 x) {
    int xi = __builtin_bit_cast(int, x);
    int r = __builtin_amdgcn_update_dpp(xi, xi, 0x121, 0xF, 0xF, false); // ROW_ROR:1
    return __builtin_bit_cast(h2, r);
}
__device__ __forceinline__ h2 ror4h(h2 x) {
    int xi = __builtin_bit_cast(int, x);
    int r = __builtin_amdgcn_update_dpp(xi, xi, 0x124, 0xF, 0xF, false); // ROW_ROR:4
    return __builtin_bit_cast(h2, r);
}

// ---------------- pack: ctrl byte (tag | tidx<<4) + in-block gold trans/start reduce ----
// Block b == sequence b (256 threads = 256 timesteps). Reduces g in-block and
// writes ONE float per seq (goldsum) -- kills the 8MB goldp write+read and gold_red.
__global__ __launch_bounds__(256) void pack_ctrl(
    const int* __restrict__ tags, const int* __restrict__ w2w,
    const int* __restrict__ ic,   const int* __restrict__ ds,
    const float* __restrict__ cw, const float* __restrict__ trans,
    const float* __restrict__ start,
    unsigned char* __restrict__ ctrl, float* __restrict__ goldsum)
{
    __shared__ float wsum[4];
    int idx = blockIdx.x * 256 + threadIdx.x;   // b*256 + t
    int b = blockIdx.x, t = threadIdx.x;
    int tag = tags[idx];
    unsigned char byte = (unsigned char)tag;
    float g;
    if (t == 0) {
        g = cw[tag] * start[tag];
    } else {
        int off = b * (T_LEN - 1) + (t - 1);
        int tidx = (w2w[off] == 1) ? 0 : ((ic[off] == 0) ? 1 : ((ds[off] == 0) ? 2 : 3));
        byte |= (unsigned char)(tidx << 4);
        g = cw[tag] * trans[tidx * 256 + tags[idx - 1] * 16 + tag];
    }
    ctrl[idx] = byte;

    float s = g;
#pragma unroll
    for (int m = 1; m < 64; m <<= 1) s += __shfl_xor(s, m, 64);
    if ((threadIdx.x & 63) == 0) wsum[threadIdx.x >> 6] = s;
    __syncthreads();
    if (threadIdx.x == 0) goldsum[b] = (wsum[0] + wsum[1]) + (wsum[2] + wsum[3]);
}

// ---------------- recurrence: 4 seqs/wave, 2048 waves, dot2-f16 matvec ----------------
// E-row select via LDS (Dl[c][j][r], two ds_read_b128/step), prefetched TWO steps
// ahead into a 4-slot ring (all indices compile-time under the unrolled blocks).
__global__ __launch_bounds__(256, 2) void crf_rec(
    const float* __restrict__ em, const float* __restrict__ trans,
    const float* __restrict__ start, const float* __restrict__ cw,
    const unsigned char* __restrict__ ctrl,
    const float* __restrict__ goldsum, float* __restrict__ out)
{
    __shared__ float tl[1024];
    __shared__ __align__(16) unsigned char Dl[3072];  // [c]*768 + [j]*48 + [r]*4, h2 entries

    for (int i = threadIdx.x; i < 1024; i += 256) tl[i] = trans[i];
    __syncthreads();

    const int j = threadIdx.x & 15;

    // DPP rotation-direction probe (proven in R1/R2); delta is lane-uniform
    int pr    = __builtin_amdgcn_update_dpp(j, j, 0x121, 0xF, 0xF, false);
    int delta = (pr - j) & 15;

    // Build Dl: 256 threads x 2 entries = 4*16*8 h2
    {
        int c  = threadIdx.x >> 6;
        int jj = (threadIdx.x >> 2) & 15;
        int r0 = (threadIdx.x & 3) * 2;
#pragma unroll
        for (int q = 0; q < 2; ++q) {
            int r = r0 + q;
            float lo = __expf(tl[c * 256 + ((jj + r * delta) & 15) * 16 + jj]);
            float hi = __expf(tl[c * 256 + ((jj + (r + 8) * delta) & 15) * 16 + jj]);
            *(h2*)&Dl[c * 768 + jj * 48 + r * 4] = pkrtz(lo, hi);
        }
    }
    __syncthreads();

    const int seq = (blockIdx.x * 256 + threadIdx.x) >> 4;
    const float cw_j = cw[j];
    const float st_j = start[j];
    const float* ep  = em + (size_t)seq * 4096 + j;
    const uint4* cp  = (const uint4*)(ctrl + (size_t)seq * 256);
    const unsigned char* Dbase = &Dl[j * 48];

    // 16-deep emission ring (1 f32/lane/step)
    float emr[16];
#pragma unroll
    for (int k = 0; k < 16; ++k) emr[k] = ep[k * 16];
    uint4 cq = cp[0], cqn = cp[1];

    // 4-slot E-row ring (compile-time indexed only), prefetch distance 2
    uint4 qa[4], qb[4];

    float u, ge, logC = 5.545177444479562f;   // 8*ln2: u0 pre-scaled 2^-8
    {
        int tag0 = (int)(cq.x & 15u);
        u  = __expf(st_j + emr[0]) * 0.00390625f;
        ge = (j == tag0) ? cw_j * emr[0] : 0.0f;
        emr[0] = ep[16 * 16];                  // refill slot 0 with t=16
        // preload E-rows for steps k=1 (slot 1) and k=2 (slot 2)
        unsigned c1 = (cq.x >> 12) & 3u;
        const uint4* p1 = (const uint4*)(Dbase + c1 * 768);
        qa[1] = p1[0]; qb[1] = p1[1];
        unsigned c2 = (cq.x >> 20) & 3u;
        const uint4* p2 = (const uint4*)(Dbase + c2 * 768);
        qa[2] = p2[0]; qb[2] = p2[1];
    }

    auto STEP = [&](int t, int k, bool pf) __attribute__((always_inline)) {
        // ---- prefetch E-row two steps ahead into slot (k+2)&3 ----
        {
            int kk = k + 2;                                // window pos 2..17
            const uint4& qn = (kk < 16) ? cq : cqn;
            int km = kk & 15;
            unsigned dwn = (km < 4) ? qn.x : (km < 8) ? qn.y : (km < 12) ? qn.z : qn.w;
            unsigned cn = (dwn >> (8 * (km & 3) + 4)) & 3u;
            const uint4* pn = (const uint4*)(Dbase + cn * 768);
            qa[(k + 2) & 3] = pn[0];
            qb[(k + 2) & 3] = pn[1];
        }
        unsigned dw = (k < 4) ? cq.x : (k < 8) ? cq.y : (k < 12) ? cq.z : cq.w;
        int sh = 8 * (k & 3);
        int tag = (int)((dw >> sh) & 15u);

        // pair (u_j, u_{j+8d}) in f16; two serial ror1 chains (rot 0..3 / 4..7)
        uint4 A = qa[k & 3], B = qb[k & 3];
        float uh = ror8f(u);
        h2 P = pkrtz(u, uh);
        h2 Q = ror4h(P);
        float s0 = __builtin_amdgcn_fdot2(P, h2cast(A.x), 0.0f, false);
        float s1 = __builtin_amdgcn_fdot2(Q, h2cast(B.x), 0.0f, false);
        P = ror1h(P); Q = ror1h(Q);
        s0 = __builtin_amdgcn_fdot2(P, h2cast(A.y), s0, false);
        s1 = __builtin_amdgcn_fdot2(Q, h2cast(B.y), s1, false);
        P = ror1h(P); Q = ror1h(Q);
        s0 = __builtin_amdgcn_fdot2(P, h2cast(A.z), s0, false);
        s1 = __builtin_amdgcn_fdot2(Q, h2cast(B.z), s1, false);
        P = ror1h(P); Q = ror1h(Q);
        s0 = __builtin_amdgcn_fdot2(P, h2cast(A.w), s0, false);
        s1 = __builtin_amdgcn_fdot2(Q, h2cast(B.w), s1, false);
        float s = s0 + s1;
        float exf = __builtin_exp2f(fmaf(emr[k], L2E, -RSCALE * L2E));
        if (j == tag) ge = fmaf(cw_j, emr[k], ge);   // gold em-term
        u = s * exf;
        if (pf) emr[k] = ep[(size_t)(t + 16) * 16];  // refill 16 steps ahead
        if ((k & 7) == 7) {                          // exact pow2 renorm, -4 bias
            float mx = u;
            mx = fmaxf(mx, __shfl_xor(mx, 1, 64));
            mx = fmaxf(mx, __shfl_xor(mx, 2, 64));
            mx = fmaxf(mx, __shfl_xor(mx, 4, 64));
            mx = fmaxf(mx, __shfl_xor(mx, 8, 64));
            // frexp/ldexp via exponent-field bit ops (mx > 0, normal); proven R3/R4
            int eb = (__float_as_int(mx) >> 23) & 255;   // e2 = eb - 126
            u *= __int_as_float((249 - eb) << 23);        // u * 2^(-e2-4)
            logC += (float)(eb - 122) * LN2;              // (e2+4)*ln2
        }
    };

    // block 0: t=1..15
#pragma unroll
    for (int k = 1; k < 16; ++k) STEP(k, k, true);
    // blocks 1..14 with prefetch
    for (int blk = 1; blk < 15; ++blk) {
        cq = cqn;
        cqn = cp[blk + 1];
#pragma unroll
        for (int k = 0; k < 16; ++k) STEP(blk * 16 + k, k, true);
    }
    // peeled last block: t=240..255, no em prefetch (E-prefetch reads stale cqn: harmless)
    cq = cqn;
#pragma unroll
    for (int k = 0; k < 16; ++k) STEP(240 + k, k, false);

    // group reductions
    float su = u, gs = ge;
#pragma unroll
    for (int m = 1; m < 16; m <<= 1) {
        su += __shfl_xor(su, m, 64);
        gs += __shfl_xor(gs, m, 64);
    }
    if (j == 0) {
        out[seq]         = gs + goldsum[seq];
        out[B_TOT + seq] = logf(su) + 255.0f * RSCALE + logC;
    }
}

extern "C" void kernel_launch(void* const* d_in, const int* in_sizes, int n_in,
                              void* d_out, int out_size, void* d_ws, size_t ws_size,
                              hipStream_t stream) {
    const float* emissions     = (const float*)d_in[0];
    const int*   tags          = (const int*)  d_in[1];
    const int*   who2who       = (const int*)  d_in[2];
    const int*   init_count    = (const int*)  d_in[3];
    const int*   distance      = (const int*)  d_in[4];
    const float* class_weights = (const float*)d_in[5];
    const float* trans_stack   = (const float*)d_in[6];
    const float* start_scores  = (const float*)d_in[7];
    float* out = (float*)d_out;

    char* ws = (char*)d_ws;
    unsigned char* ctrl    = (unsigned char*)ws;         // 2 MB
    float*         goldsum = (float*)(ws + (2 << 20));   // 32 KB

    hipLaunchKernelGGL(pack_ctrl, dim3(B_TOT), dim3(256), 0, stream,
                       tags, who2who, init_count, distance,
                       class_weights, trans_stack, start_scores, ctrl, goldsum);

    hipLaunchKernelGGL(crf_rec, dim3(B_TOT * 16 / 256), dim3(256), 0, stream,
                       emissions, trans_stack, start_scores, class_weights,
                       ctrl, goldsum, out);
}